// Round 1
// baseline (310.447 us; speedup 1.0000x reference)
//
#include <hip/hip_runtime.h>

#define LSEQ 2048
#define EMB  512
#define NH   8
#define HD   64
#define NBATCH 4
#define SCALE 0.044194173824159216f   // 1/sqrt(512)

using short8  = __attribute__((ext_vector_type(8))) short;
using short4v = __attribute__((ext_vector_type(4))) short;
using f32x4   = __attribute__((ext_vector_type(4))) float;

__device__ __forceinline__ short bf16r(float f) {
  union { float f; unsigned u; } x; x.f = f;
  unsigned r = x.u + 0x7FFFu + ((x.u >> 16) & 1u);
  return (short)(r >> 16);
}

// load 8 consecutive f32 from global, round to bf16 fragment
__device__ __forceinline__ short8 cvt8(const float* __restrict__ p) {
  float4 a = ((const float4*)p)[0];
  float4 b = ((const float4*)p)[1];
  short8 r;
  r[0]=bf16r(a.x); r[1]=bf16r(a.y); r[2]=bf16r(a.z); r[3]=bf16r(a.w);
  r[4]=bf16r(b.x); r[5]=bf16r(b.y); r[6]=bf16r(b.z); r[7]=bf16r(b.w);
  return r;
}

__device__ __forceinline__ short8 ld8(const short* __restrict__ p) {
  return *(const short8*)p;
}

// ---------------------------------------------------------------- Wo -> bf16
__global__ __launch_bounds__(256) void cvt_wo(const float* __restrict__ Wo,
                                              short* __restrict__ Wob) {
  int i = blockIdx.x * 256 + threadIdx.x;         // 65536 threads, 4 f32 each
  float4 v = ((const float4*)Wo)[i];
  short4v r;
  r[0]=bf16r(v.x); r[1]=bf16r(v.y); r[2]=bf16r(v.z); r[3]=bf16r(v.w);
  ((short4v*)Wob)[i] = r;
}

// ------------------------------------------------- per-head QKV projections
// grid.x: (n,h,ltile) 1024 blocks; grid.y: tensor 0=Q 1=K 2=V
// out[l][e] = sum_d x[l][d] * W[e][d]   (x rows 64 per block, 4 waves x 16)
__global__ __launch_bounds__(256) void proj_kernel(
    const float* __restrict__ query, const float* __restrict__ keys,
    const float* __restrict__ values,
    const float* __restrict__ Wq, const float* __restrict__ Wk,
    const float* __restrict__ Wv,
    short* __restrict__ Qp, short* __restrict__ Kp, short* __restrict__ Vt) {
  int t = blockIdx.y;
  const float* x = (t == 0) ? query : (t == 1) ? keys : values;
  const float* W = (t == 0) ? Wq    : (t == 1) ? Wk   : Wv;
  int idx = blockIdx.x;
  int lt = idx & 31, h = (idx >> 5) & 7, n = idx >> 8;
  int tid = threadIdx.x, lane = tid & 63, w = tid >> 6;
  int row16 = lane & 15, g = lane >> 4;
  int lbase = lt * 64 + w * 16;

  // A fragment: 16 rows (l) x 64 (d), two K=32 halves
  const float* xr = x + ((size_t)(n * LSEQ + lbase + row16)) * EMB + h * HD + g * 8;
  short8 a0 = cvt8(xr);
  short8 a1 = cvt8(xr + 32);

  f32x4 acc[4];
#pragma unroll
  for (int et = 0; et < 4; et++) acc[et] = (f32x4){0.f, 0.f, 0.f, 0.f};
#pragma unroll
  for (int et = 0; et < 4; et++) {
    const float* wr = W + (size_t)(et * 16 + row16) * HD + g * 8;  // W[e][d] row
    short8 b0 = cvt8(wr);
    short8 b1 = cvt8(wr + 32);
    acc[et] = __builtin_amdgcn_mfma_f32_16x16x32_bf16(a0, b0, acc[et], 0, 0, 0);
    acc[et] = __builtin_amdgcn_mfma_f32_16x16x32_bf16(a1, b1, acc[et], 0, 0, 0);
  }

  if (t == 2) {  // V stored transposed: Vt[n][h][d][L]
#pragma unroll
    for (int et = 0; et < 4; et++)
#pragma unroll
      for (int r = 0; r < 4; r++) {
        int d = et * 16 + row16;
        int l = lbase + g * 4 + r;
        Vt[((size_t)((n * NH + h) * HD + d)) * LSEQ + l] = bf16r(acc[et][r]);
      }
  } else {       // Q/K: [n][h][l][d]
    short* O = (t == 0) ? Qp : Kp;
#pragma unroll
    for (int et = 0; et < 4; et++)
#pragma unroll
      for (int r = 0; r < 4; r++) {
        int l = lbase + g * 4 + r;
        O[((size_t)((n * NH + h) * LSEQ + l)) * HD + et * 16 + row16] =
            bf16r(acc[et][r]);
      }
  }
}

// ------------------------------------------------------------ flash attention
// block = (n,h,qtile of 64); 4 waves, each wave: 16 q-rows x full d=64
__global__ __launch_bounds__(256) void attn_kernel(
    const short* __restrict__ Qp, const short* __restrict__ Kp,
    const short* __restrict__ Vt, const int* __restrict__ mask,
    short* __restrict__ aout) {
  __shared__ int mask_l[LSEQ];                       // 8 KB
  __shared__ __align__(16) short P_lds[4][16][72];   // +8 pad -> 144B rows

  int idx = blockIdx.x;
  int qt = idx & 31, h = (idx >> 5) & 7, n = idx >> 8;
  int tid = threadIdx.x, lane = tid & 63, w = tid >> 6;
  int row16 = lane & 15, g = lane >> 4;

  for (int i = tid; i < LSEQ; i += 256) mask_l[i] = mask[n * LSEQ + i];
  __syncthreads();

  size_t nh = (size_t)(n * NH + h);
  const short* Qb = Qp + (nh * LSEQ + qt * 64 + w * 16) * HD;
  short8 aq0 = ld8(Qb + row16 * HD + g * 8);
  short8 aq1 = ld8(Qb + row16 * HD + 32 + g * 8);

  f32x4 acc[4];
#pragma unroll
  for (int dt = 0; dt < 4; dt++) acc[dt] = (f32x4){0.f, 0.f, 0.f, 0.f};
  float m[4], lsum[4];
#pragma unroll
  for (int r = 0; r < 4; r++) { m[r] = -3e38f; lsum[r] = 0.f; }

  const short* Kb0 = Kp + nh * LSEQ * HD;
  const short* Vb0 = Vt + nh * HD * LSEQ;

  for (int kt = 0; kt < LSEQ / 64; kt++) {
    int kb = kt * 64;
    // ---- S = Q K^T (16q x 64k), 4 sub-tiles of 16 keys
    f32x4 s[4];
#pragma unroll
    for (int ks = 0; ks < 4; ks++) {
      const short* Kb = Kb0 + (size_t)(kb + ks * 16) * HD;
      short8 b0 = ld8(Kb + row16 * HD + g * 8);
      short8 b1 = ld8(Kb + row16 * HD + 32 + g * 8);
      f32x4 t = (f32x4){0.f, 0.f, 0.f, 0.f};
      t = __builtin_amdgcn_mfma_f32_16x16x32_bf16(aq0, b0, t, 0, 0, 0);
      t = __builtin_amdgcn_mfma_f32_16x16x32_bf16(aq1, b1, t, 0, 0, 0);
      s[ks] = t;
    }
    // ---- mask + scale + online softmax
    int mk[4];
#pragma unroll
    for (int ks = 0; ks < 4; ks++) mk[ks] = mask_l[kb + ks * 16 + row16];
    float tmax[4];
#pragma unroll
    for (int r = 0; r < 4; r++) tmax[r] = -3e38f;
#pragma unroll
    for (int ks = 0; ks < 4; ks++)
#pragma unroll
      for (int r = 0; r < 4; r++) {
        float v = s[ks][r] * SCALE;
        s[ks][r] = v;
        if (mk[ks]) tmax[r] = fmaxf(tmax[r], v);
      }
#pragma unroll
    for (int off = 1; off < 16; off <<= 1)
#pragma unroll
      for (int r = 0; r < 4; r++)
        tmax[r] = fmaxf(tmax[r], __shfl_xor(tmax[r], off));
    float mn[4], sf[4], ps[4];
#pragma unroll
    for (int r = 0; r < 4; r++) {
      mn[r] = fmaxf(m[r], tmax[r]);
      sf[r] = (m[r] >= mn[r]) ? 1.f : __expf(m[r] - mn[r]);
      ps[r] = 0.f;
    }
#pragma unroll
    for (int ks = 0; ks < 4; ks++)
#pragma unroll
      for (int r = 0; r < 4; r++) {
        float p = mk[ks] ? __expf(s[ks][r] - mn[r]) : 0.f;
        ps[r] += p;
        P_lds[w][g * 4 + r][ks * 16 + row16] = bf16r(p);
      }
#pragma unroll
    for (int off = 1; off < 16; off <<= 1)
#pragma unroll
      for (int r = 0; r < 4; r++) ps[r] += __shfl_xor(ps[r], off);
#pragma unroll
    for (int r = 0; r < 4; r++) {
      lsum[r] = lsum[r] * sf[r] + ps[r];
      m[r] = mn[r];
    }
#pragma unroll
    for (int dt = 0; dt < 4; dt++)
#pragma unroll
      for (int r = 0; r < 4; r++) acc[dt][r] *= sf[r];

    // ---- O += P V  (P via LDS reshape; V^T gives contiguous key loads)
    short8 ap0 = ld8(&P_lds[w][row16][g * 8]);
    short8 ap1 = ld8(&P_lds[w][row16][32 + g * 8]);
#pragma unroll
    for (int dt = 0; dt < 4; dt++) {
      const short* Vb = Vb0 + (size_t)(dt * 16 + row16) * LSEQ + kb;
      short8 bv0 = ld8(Vb + g * 8);
      short8 bv1 = ld8(Vb + 32 + g * 8);
      acc[dt] = __builtin_amdgcn_mfma_f32_16x16x32_bf16(ap0, bv0, acc[dt], 0, 0, 0);
      acc[dt] = __builtin_amdgcn_mfma_f32_16x16x32_bf16(ap1, bv1, acc[dt], 0, 0, 0);
    }
  }

  // ---- epilogue: normalize, write [n][q][h*64+d] bf16
#pragma unroll
  for (int r = 0; r < 4; r++) {
    float inv = lsum[r] > 0.f ? 1.f / lsum[r] : 0.f;
    int q = qt * 64 + w * 16 + g * 4 + r;
#pragma unroll
    for (int dt = 0; dt < 4; dt++)
      aout[((size_t)(n * LSEQ + q)) * EMB + h * HD + dt * 16 + row16] =
          bf16r(acc[dt][r] * inv);
  }
}

// --------------------------------------------------- final projection + bias
// out[8192][512] = aout(bf16) @ Wo^T + bo ; block: 64 rows x 64 cols
__global__ __launch_bounds__(256) void outproj_kernel(
    const short* __restrict__ aout, const short* __restrict__ Wob,
    const float* __restrict__ bo, float* __restrict__ out) {
  int mt = blockIdx.x, nt = blockIdx.y;
  int tid = threadIdx.x, lane = tid & 63, w = tid >> 6;
  int row16 = lane & 15, g = lane >> 4;
  int mrow = mt * 64 + w * 16;

  f32x4 acc[4];
#pragma unroll
  for (int et = 0; et < 4; et++) acc[et] = (f32x4){0.f, 0.f, 0.f, 0.f};

  for (int kc = 0; kc < 16; kc++) {
    short8 a = ld8(aout + (size_t)(mrow + row16) * EMB + kc * 32 + g * 8);
#pragma unroll
    for (int et = 0; et < 4; et++) {
      short8 b = ld8(Wob + (size_t)(nt * 64 + et * 16 + row16) * EMB + kc * 32 + g * 8);
      acc[et] = __builtin_amdgcn_mfma_f32_16x16x32_bf16(a, b, acc[et], 0, 0, 0);
    }
  }
#pragma unroll
  for (int et = 0; et < 4; et++) {
    int e = nt * 64 + et * 16 + row16;
    float bias = bo[e];
#pragma unroll
    for (int r = 0; r < 4; r++) {
      int row = mrow + g * 4 + r;
      out[(size_t)row * EMB + e] = acc[et][r] + bias;
    }
  }
}

extern "C" void kernel_launch(void* const* d_in, const int* in_sizes, int n_in,
                              void* d_out, int out_size, void* d_ws, size_t ws_size,
                              hipStream_t stream) {
  const float* values = (const float*)d_in[0];
  const float* keys   = (const float*)d_in[1];
  const float* query  = (const float*)d_in[2];
  const int*   mask   = (const int*)d_in[3];
  const float* Wv     = (const float*)d_in[4];
  const float* Wk     = (const float*)d_in[5];
  const float* Wq     = (const float*)d_in[6];
  const float* Wo     = (const float*)d_in[7];
  const float* bo     = (const float*)d_in[8];
  float* out = (float*)d_out;

  // Qp/Kp scratch lives in d_out (16 MB, overwritten by outproj at the end;
  // stream-ordered so no hazard, and deterministic per call).
  short* Qp = (short*)d_out;
  short* Kp = (short*)((char*)d_out + (8u << 20));
  char* ws = (char*)d_ws;
  short* Vt   = (short*)(ws);                  //  8 MB  [n][h][64][2048]
  short* aout = (short*)(ws + (8u << 20));     //  8 MB  [n*2048][512]
  short* Wob  = (short*)(ws + (16u << 20));    // 0.5 MB

  cvt_wo<<<256, 256, 0, stream>>>(Wo, Wob);
  proj_kernel<<<dim3(NBATCH * NH * (LSEQ / 64), 3), 256, 0, stream>>>(
      query, keys, values, Wq, Wk, Wv, Qp, Kp, Vt);
  attn_kernel<<<NBATCH * NH * (LSEQ / 64), 256, 0, stream>>>(Qp, Kp, Vt, mask, aout);
  outproj_kernel<<<dim3((NBATCH * LSEQ) / 64, EMB / 64), 256, 0, stream>>>(
      aout, Wob, bo, out);
}

// Round 2
// 309.962 us; speedup vs baseline: 1.0016x; 1.0016x over previous
//
#include <hip/hip_runtime.h>

#define LSEQ 2048
#define EMB  512
#define NH   8
#define HD   64
#define NBATCH 4
// 1/sqrt(512) * log2(e): folded into Q projection; softmax runs in exp2 domain
#define QSCALE (0.044194173824159216f * 1.4426950408889634f)

using short8  = __attribute__((ext_vector_type(8))) short;
using short4v = __attribute__((ext_vector_type(4))) short;
using f32x4   = __attribute__((ext_vector_type(4))) float;

__device__ __forceinline__ short bf16r(float f) {
  union { float f; unsigned u; } x; x.f = f;
  unsigned r = x.u + 0x7FFFu + ((x.u >> 16) & 1u);
  return (short)(r >> 16);
}

__device__ __forceinline__ float exp2v(float x) {
  float r;
  asm("v_exp_f32 %0, %1" : "=v"(r) : "v"(x));   // D = 2^S0
  return r;
}

// load 8 consecutive f32 from global, round to bf16 fragment
__device__ __forceinline__ short8 cvt8(const float* __restrict__ p) {
  float4 a = ((const float4*)p)[0];
  float4 b = ((const float4*)p)[1];
  short8 r;
  r[0]=bf16r(a.x); r[1]=bf16r(a.y); r[2]=bf16r(a.z); r[3]=bf16r(a.w);
  r[4]=bf16r(b.x); r[5]=bf16r(b.y); r[6]=bf16r(b.z); r[7]=bf16r(b.w);
  return r;
}

__device__ __forceinline__ short8 ld8(const short* __restrict__ p) {
  return *(const short8*)p;
}

// ---------------------------------------------------------------- Wo -> bf16
__global__ __launch_bounds__(256) void cvt_wo(const float* __restrict__ Wo,
                                              short* __restrict__ Wob) {
  int i = blockIdx.x * 256 + threadIdx.x;
  float4 v = ((const float4*)Wo)[i];
  short4v r;
  r[0]=bf16r(v.x); r[1]=bf16r(v.y); r[2]=bf16r(v.z); r[3]=bf16r(v.w);
  ((short4v*)Wob)[i] = r;
}

// ------------------------------------------------- per-head QKV projections
// Q output pre-scaled by QSCALE so attention softmax runs in exp2 domain.
__global__ __launch_bounds__(256) void proj_kernel(
    const float* __restrict__ query, const float* __restrict__ keys,
    const float* __restrict__ values,
    const float* __restrict__ Wq, const float* __restrict__ Wk,
    const float* __restrict__ Wv,
    short* __restrict__ Qp, short* __restrict__ Kp, short* __restrict__ Vt) {
  int t = blockIdx.y;
  const float* x = (t == 0) ? query : (t == 1) ? keys : values;
  const float* W = (t == 0) ? Wq    : (t == 1) ? Wk   : Wv;
  int idx = blockIdx.x;
  int lt = idx & 31, h = (idx >> 5) & 7, n = idx >> 8;
  int tid = threadIdx.x, lane = tid & 63, w = tid >> 6;
  int row16 = lane & 15, g = lane >> 4;
  int lbase = lt * 64 + w * 16;

  const float* xr = x + ((size_t)(n * LSEQ + lbase + row16)) * EMB + h * HD + g * 8;
  short8 a0 = cvt8(xr);
  short8 a1 = cvt8(xr + 32);

  f32x4 acc[4];
#pragma unroll
  for (int et = 0; et < 4; et++) acc[et] = (f32x4){0.f, 0.f, 0.f, 0.f};
#pragma unroll
  for (int et = 0; et < 4; et++) {
    const float* wr = W + (size_t)(et * 16 + row16) * HD + g * 8;
    short8 b0 = cvt8(wr);
    short8 b1 = cvt8(wr + 32);
    acc[et] = __builtin_amdgcn_mfma_f32_16x16x32_bf16(a0, b0, acc[et], 0, 0, 0);
    acc[et] = __builtin_amdgcn_mfma_f32_16x16x32_bf16(a1, b1, acc[et], 0, 0, 0);
  }

  float sc = (t == 0) ? QSCALE : 1.f;
  if (t == 2) {  // V transposed: Vt[n][h][d][L]
#pragma unroll
    for (int et = 0; et < 4; et++)
#pragma unroll
      for (int r = 0; r < 4; r++) {
        int d = et * 16 + row16;
        int l = lbase + g * 4 + r;
        Vt[((size_t)((n * NH + h) * HD + d)) * LSEQ + l] = bf16r(acc[et][r]);
      }
  } else {
    short* O = (t == 0) ? Qp : Kp;
#pragma unroll
    for (int et = 0; et < 4; et++)
#pragma unroll
      for (int r = 0; r < 4; r++) {
        int l = lbase + g * 4 + r;
        O[((size_t)((n * NH + h) * LSEQ + l)) * HD + et * 16 + row16] =
            bf16r(acc[et][r] * sc);
      }
  }
}

// ------------------------------------------------------------ flash attention
// block = (n,h,qtile of 64); 4 waves, each wave: 16 q-rows x full d=64.
// All K/V/mask loads for a tile issued in one batch at iteration top
// (single latency exposure); softmax in exp2 domain with defer-max skip.
__global__ __launch_bounds__(256) void attn_kernel(
    const short* __restrict__ Qp, const short* __restrict__ Kp,
    const short* __restrict__ Vt, const int* __restrict__ mask,
    short* __restrict__ aout) {
  __shared__ int mask_l[LSEQ];                       // 8 KB
  __shared__ __align__(16) short P_lds[4][16][76];   // 152B rows (=6 dw mod 32)

  int idx = blockIdx.x;
  int qt = idx & 31, h = (idx >> 5) & 7, n = idx >> 8;
  int tid = threadIdx.x, lane = tid & 63, w = tid >> 6;
  int row16 = lane & 15, g = lane >> 4;

  for (int i = tid; i < LSEQ; i += 256) mask_l[i] = mask[n * LSEQ + i];
  __syncthreads();

  size_t nh = (size_t)(n * NH + h);
  const short* Qb = Qp + (nh * LSEQ + qt * 64 + w * 16) * HD;
  short8 aq0 = ld8(Qb + row16 * HD + g * 8);
  short8 aq1 = ld8(Qb + row16 * HD + 32 + g * 8);

  f32x4 acc[4];
#pragma unroll
  for (int dt = 0; dt < 4; dt++) acc[dt] = (f32x4){0.f, 0.f, 0.f, 0.f};
  float m[4], lsum[4];
#pragma unroll
  for (int r = 0; r < 4; r++) { m[r] = -3e38f; lsum[r] = 0.f; }

  const short* Kb0 = Kp + nh * LSEQ * HD;
  const short* Vb0 = Vt + nh * HD * LSEQ;

  for (int kt = 0; kt < LSEQ / 64; kt++) {
    int kb = kt * 64;
    // ---- issue ALL loads for this tile up front (one latency exposure)
    short8 kf0[4], kf1[4], vf0[4], vf1[4];
#pragma unroll
    for (int ks = 0; ks < 4; ks++) {
      const short* Kb = Kb0 + (size_t)(kb + ks * 16 + row16) * HD + g * 8;
      kf0[ks] = ld8(Kb);
      kf1[ks] = ld8(Kb + 32);
    }
#pragma unroll
    for (int dt = 0; dt < 4; dt++) {
      const short* Vb = Vb0 + (size_t)(dt * 16 + row16) * LSEQ + kb + g * 8;
      vf0[dt] = ld8(Vb);
      vf1[dt] = ld8(Vb + 32);
    }
    int mk[4];
#pragma unroll
    for (int ks = 0; ks < 4; ks++) mk[ks] = mask_l[kb + ks * 16 + row16];

    // ---- S = Q K^T (16q x 64k)
    f32x4 s[4];
    __builtin_amdgcn_s_setprio(1);
#pragma unroll
    for (int ks = 0; ks < 4; ks++) {
      f32x4 t = (f32x4){0.f, 0.f, 0.f, 0.f};
      t = __builtin_amdgcn_mfma_f32_16x16x32_bf16(aq0, kf0[ks], t, 0, 0, 0);
      t = __builtin_amdgcn_mfma_f32_16x16x32_bf16(aq1, kf1[ks], t, 0, 0, 0);
      s[ks] = t;
    }
    __builtin_amdgcn_s_setprio(0);

    // ---- mask into s (exp2(-1e30) == 0 handles masked lanes downstream)
#pragma unroll
    for (int ks = 0; ks < 4; ks++)
#pragma unroll
      for (int r = 0; r < 4; r++)
        s[ks][r] = mk[ks] ? s[ks][r] : -1e30f;

    // ---- row max of this tile
    float tmax[4];
#pragma unroll
    for (int r = 0; r < 4; r++)
      tmax[r] = fmaxf(fmaxf(s[0][r], s[1][r]), fmaxf(s[2][r], s[3][r]));
#pragma unroll
    for (int off = 1; off < 16; off <<= 1)
#pragma unroll
      for (int r = 0; r < 4; r++)
        tmax[r] = fmaxf(tmax[r], __shfl_xor(tmax[r], off));

    // ---- defer-max: only rescale when tile max grew past threshold (T13)
    int grew = !((tmax[0] <= m[0] + 8.f) & (tmax[1] <= m[1] + 8.f) &
                 (tmax[2] <= m[2] + 8.f) & (tmax[3] <= m[3] + 8.f));
    if (__any(grew)) {
#pragma unroll
      for (int r = 0; r < 4; r++) {
        float mn = fmaxf(m[r], tmax[r]);
        float sf = exp2v(m[r] - mn);
        lsum[r] *= sf;
        m[r] = mn;
#pragma unroll
        for (int dt = 0; dt < 4; dt++) acc[dt][r] *= sf;
      }
    }

    // ---- p = exp2(s - m), partial sums, stage P to LDS
    float ps[4];
#pragma unroll
    for (int r = 0; r < 4; r++) ps[r] = 0.f;
#pragma unroll
    for (int ks = 0; ks < 4; ks++)
#pragma unroll
      for (int r = 0; r < 4; r++) {
        float p = exp2v(s[ks][r] - m[r]);
        ps[r] += p;
        P_lds[w][g * 4 + r][ks * 16 + row16] = bf16r(p);
      }
#pragma unroll
    for (int off = 1; off < 16; off <<= 1)
#pragma unroll
      for (int r = 0; r < 4; r++) ps[r] += __shfl_xor(ps[r], off);
#pragma unroll
    for (int r = 0; r < 4; r++) lsum[r] += ps[r];

    // ---- O += P V
    short8 ap0 = ld8(&P_lds[w][row16][g * 8]);
    short8 ap1 = ld8(&P_lds[w][row16][32 + g * 8]);
    __builtin_amdgcn_s_setprio(1);
#pragma unroll
    for (int dt = 0; dt < 4; dt++) {
      acc[dt] = __builtin_amdgcn_mfma_f32_16x16x32_bf16(ap0, vf0[dt], acc[dt], 0, 0, 0);
      acc[dt] = __builtin_amdgcn_mfma_f32_16x16x32_bf16(ap1, vf1[dt], acc[dt], 0, 0, 0);
    }
    __builtin_amdgcn_s_setprio(0);
  }

  // ---- epilogue: normalize, write [n][q][h*64+d] bf16
#pragma unroll
  for (int r = 0; r < 4; r++) {
    float inv = lsum[r] > 0.f ? 1.f / lsum[r] : 0.f;
    int q = qt * 64 + w * 16 + g * 4 + r;
#pragma unroll
    for (int dt = 0; dt < 4; dt++)
      aout[((size_t)(n * LSEQ + q)) * EMB + h * HD + dt * 16 + row16] =
          bf16r(acc[dt][r] * inv);
  }
}

// --------------------------------------------------- final projection + bias
__global__ __launch_bounds__(256) void outproj_kernel(
    const short* __restrict__ aout, const short* __restrict__ Wob,
    const float* __restrict__ bo, float* __restrict__ out) {
  int mt = blockIdx.x, nt = blockIdx.y;
  int tid = threadIdx.x, lane = tid & 63, w = tid >> 6;
  int row16 = lane & 15, g = lane >> 4;
  int mrow = mt * 64 + w * 16;

  f32x4 acc[4];
#pragma unroll
  for (int et = 0; et < 4; et++) acc[et] = (f32x4){0.f, 0.f, 0.f, 0.f};

  for (int kc = 0; kc < 16; kc++) {
    short8 a = ld8(aout + (size_t)(mrow + row16) * EMB + kc * 32 + g * 8);
#pragma unroll
    for (int et = 0; et < 4; et++) {
      short8 b = ld8(Wob + (size_t)(nt * 64 + et * 16 + row16) * EMB + kc * 32 + g * 8);
      acc[et] = __builtin_amdgcn_mfma_f32_16x16x32_bf16(a, b, acc[et], 0, 0, 0);
    }
  }
#pragma unroll
  for (int et = 0; et < 4; et++) {
    int e = nt * 64 + et * 16 + row16;
    float bias = bo[e];
#pragma unroll
    for (int r = 0; r < 4; r++) {
      int row = mrow + g * 4 + r;
      out[(size_t)row * EMB + e] = acc[et][r] + bias;
    }
  }
}

extern "C" void kernel_launch(void* const* d_in, const int* in_sizes, int n_in,
                              void* d_out, int out_size, void* d_ws, size_t ws_size,
                              hipStream_t stream) {
  const float* values = (const float*)d_in[0];
  const float* keys   = (const float*)d_in[1];
  const float* query  = (const float*)d_in[2];
  const int*   mask   = (const int*)d_in[3];
  const float* Wv     = (const float*)d_in[4];
  const float* Wk     = (const float*)d_in[5];
  const float* Wq     = (const float*)d_in[6];
  const float* Wo     = (const float*)d_in[7];
  const float* bo     = (const float*)d_in[8];
  float* out = (float*)d_out;

  // Qp/Kp scratch lives in d_out (16 MB, overwritten by outproj at the end;
  // stream-ordered so no hazard, and deterministic per call).
  short* Qp = (short*)d_out;
  short* Kp = (short*)((char*)d_out + (8u << 20));
  char* ws = (char*)d_ws;
  short* Vt   = (short*)(ws);                  //  8 MB  [n][h][64][2048]
  short* aout = (short*)(ws + (8u << 20));     //  8 MB  [n*2048][512]
  short* Wob  = (short*)(ws + (16u << 20));    // 0.5 MB

  cvt_wo<<<256, 256, 0, stream>>>(Wo, Wob);
  proj_kernel<<<dim3(NBATCH * NH * (LSEQ / 64), 3), 256, 0, stream>>>(
      query, keys, values, Wq, Wk, Wv, Qp, Kp, Vt);
  attn_kernel<<<NBATCH * NH * (LSEQ / 64), 256, 0, stream>>>(Qp, Kp, Vt, mask, aout);
  outproj_kernel<<<dim3((NBATCH * LSEQ) / 64, EMB / 64), 256, 0, stream>>>(
      aout, Wob, bo, out);
}